// Round 1
// baseline (523.199 us; speedup 1.0000x reference)
//
#include <hip/hip_runtime.h>

#define D_FEAT 128
#define F4     (D_FEAT / 4)     // 32 float4 per node row
#define BLOCK  512              // 8 waves
#define EPS    1e-6f

// ---- block-cooperative prefix: start-node offset of graph g (BLOCK=512) ----
__device__ __forceinline__ int graph_offset(const int* __restrict__ n_node,
                                            int g, int t)
{
    __shared__ int s_red[8];
    __shared__ int s_off;
    int my = 0;
    for (int i = t; i < g; i += BLOCK) my += n_node[i];
    #pragma unroll
    for (int o = 32; o; o >>= 1) my += __shfl_down(my, o);
    if ((t & 63) == 0) s_red[t >> 6] = my;
    __syncthreads();
    if (t == 0) {
        int tot = 0;
        #pragma unroll
        for (int w = 0; w < 8; w++) tot += s_red[w];
        s_off = tot;
    }
    __syncthreads();
    return s_off;
}

// =====================================================================
// Kernel 1: per-graph streaming stats -> per-feature affine coefficients
//   mode 0: A,B stored to coef[]   (coef = workspace, float4 granularity)
//   mode 1: A,B staged into the first 2 node-rows of y's graph region
// =====================================================================
__global__ __launch_bounds__(BLOCK, 8) void gn_stats(
    const float* __restrict__ x,
    const int*   __restrict__ n_node,
    const float* __restrict__ mean_scale,
    const float* __restrict__ scale,
    const float* __restrict__ bias,
    float*       __restrict__ y,
    float4*      __restrict__ coef,
    int n_graph, int mode)
{
    const int g    = blockIdx.x;
    const int t    = threadIdx.x;
    const int grp  = t & 31;     // which float4 of the 128-feat row
    const int nsub = t >> 5;     // 0..15 : node sub-index (stride 16)
    const int wave = t >> 6;     // 0..7
    const int lane = t & 63;

    const int node0 = graph_offset(n_node, g, t);
    const int cnt   = n_node[g];

    const float4* __restrict__ xg = (const float4*)x + (size_t)node0 * F4;

    float4 sum = make_float4(0.f, 0.f, 0.f, 0.f);
    float4 sq  = make_float4(0.f, 0.f, 0.f, 0.f);

    // ---- streaming accumulate, unroll 4 (4 loads in flight/thread) ----
    int node = nsub;
    for (; node + 48 < cnt; node += 64) {
        float4 v0 = xg[(size_t)(node     ) * F4 + grp];
        float4 v1 = xg[(size_t)(node + 16) * F4 + grp];
        float4 v2 = xg[(size_t)(node + 32) * F4 + grp];
        float4 v3 = xg[(size_t)(node + 48) * F4 + grp];
        sum.x += v0.x + v1.x + v2.x + v3.x;
        sum.y += v0.y + v1.y + v2.y + v3.y;
        sum.z += v0.z + v1.z + v2.z + v3.z;
        sum.w += v0.w + v1.w + v2.w + v3.w;
        sq.x += v0.x*v0.x + v1.x*v1.x + v2.x*v2.x + v3.x*v3.x;
        sq.y += v0.y*v0.y + v1.y*v1.y + v2.y*v2.y + v3.y*v3.y;
        sq.z += v0.z*v0.z + v1.z*v1.z + v2.z*v2.z + v3.z*v3.z;
        sq.w += v0.w*v0.w + v1.w*v1.w + v2.w*v2.w + v3.w*v3.w;
    }
    for (; node < cnt; node += 16) {
        float4 v0 = xg[(size_t)node * F4 + grp];
        sum.x += v0.x; sum.y += v0.y; sum.z += v0.z; sum.w += v0.w;
        sq.x += v0.x*v0.x; sq.y += v0.y*v0.y;
        sq.z += v0.z*v0.z; sq.w += v0.w*v0.w;
    }

    // ---- reduce: lanes 32..63 -> 0..31 within wave ----
    sum.x += __shfl_down(sum.x, 32); sum.y += __shfl_down(sum.y, 32);
    sum.z += __shfl_down(sum.z, 32); sum.w += __shfl_down(sum.w, 32);
    sq.x  += __shfl_down(sq.x, 32);  sq.y  += __shfl_down(sq.y, 32);
    sq.z  += __shfl_down(sq.z, 32);  sq.w  += __shfl_down(sq.w, 32);

    __shared__ float4 s_sum[8][32];
    __shared__ float4 s_sq [8][32];
    if (lane < 32) { s_sum[wave][lane] = sum; s_sq[wave][lane] = sq; }
    __syncthreads();

    if (t < 32) {
        const float inv = 1.0f / (float)cnt;
        float4 S = make_float4(0.f, 0.f, 0.f, 0.f);
        float4 Q = make_float4(0.f, 0.f, 0.f, 0.f);
        #pragma unroll
        for (int w = 0; w < 8; w++) {
            float4 a4 = s_sum[w][t];
            float4 b4 = s_sq[w][t];
            S.x += a4.x; S.y += a4.y; S.z += a4.z; S.w += a4.w;
            Q.x += b4.x; Q.y += b4.y; Q.z += b4.z; Q.w += b4.w;
        }
        const float4 ms = ((const float4*)mean_scale)[t];
        const float4 sc = ((const float4*)scale)[t];
        const float4 bs = ((const float4*)bias)[t];

        float4 A, B;
        {
            float mean = S.x * inv, m = mean * ms.x;
            float var  = Q.x * inv - 2.f * m * mean + m * m;
            A.x = rsqrtf(var + EPS) * sc.x; B.x = bs.x - m * A.x;
        }
        {
            float mean = S.y * inv, m = mean * ms.y;
            float var  = Q.y * inv - 2.f * m * mean + m * m;
            A.y = rsqrtf(var + EPS) * sc.y; B.y = bs.y - m * A.y;
        }
        {
            float mean = S.z * inv, m = mean * ms.z;
            float var  = Q.z * inv - 2.f * m * mean + m * m;
            A.z = rsqrtf(var + EPS) * sc.z; B.z = bs.z - m * A.z;
        }
        {
            float mean = S.w * inv, m = mean * ms.w;
            float var  = Q.w * inv - 2.f * m * mean + m * m;
            A.w = rsqrtf(var + EPS) * sc.w; B.w = bs.w - m * A.w;
        }

        if (mode == 0) {
            coef[(size_t)g * 32 + t]             = A;
            coef[(size_t)(n_graph + g) * 32 + t] = B;
        } else if (cnt >= 2) {
            // stage A,B in the first two node-rows of this graph's y region;
            // gn_apply reads them before overwriting (same block owns region)
            float4* ygc = (float4*)y + (size_t)node0 * F4;
            ygc[t]      = A;
            ygc[32 + t] = B;
        }
    }
}

// =====================================================================
// Kernel 2: apply y = x*A + B.  Graph order REVERSED so the re-read of x
// walks the Infinity-Cache-resident tail first (anti-LRU direction).
// =====================================================================
__global__ __launch_bounds__(BLOCK, 8) void gn_apply(
    const float* __restrict__ x,
    const int*   __restrict__ n_node,
    float*       __restrict__ y,
    const float4* __restrict__ coef,
    int n_graph, int mode)
{
    const int g    = n_graph - 1 - blockIdx.x;   // reversed mapping
    const int t    = threadIdx.x;
    const int grp  = t & 31;
    const int nsub = t >> 5;

    const int node0 = graph_offset(n_node, g, t);
    const int cnt   = n_node[g];

    __shared__ float4 s_a[32];
    __shared__ float4 s_b[32];
    if (mode == 0) {
        if (t < 32)      s_a[t]      = coef[(size_t)g * 32 + t];
        else if (t < 64) s_b[t - 32] = coef[(size_t)(n_graph + g) * 32 + (t - 32)];
    } else {
        const float4* ygc = (const float4*)y + (size_t)node0 * F4;
        if (t < 64) {
            if (t < 32) s_a[t]      = ygc[t];
            else        s_b[t - 32] = ygc[t];   // ygc[32 + (t-32)] == ygc[t]
        }
    }
    __syncthreads();

    const float4 a = s_a[grp];
    const float4 b = s_b[grp];

    const float4* __restrict__ xg = (const float4*)x + (size_t)node0 * F4;
    float4*       __restrict__ yg = (float4*)y       + (size_t)node0 * F4;

    int node = nsub;
    for (; node + 48 < cnt; node += 64) {
        float4 v0 = xg[(size_t)(node     ) * F4 + grp];
        float4 v1 = xg[(size_t)(node + 16) * F4 + grp];
        float4 v2 = xg[(size_t)(node + 32) * F4 + grp];
        float4 v3 = xg[(size_t)(node + 48) * F4 + grp];
        float4 r0, r1, r2, r3;
        r0.x = fmaf(v0.x, a.x, b.x); r0.y = fmaf(v0.y, a.y, b.y);
        r0.z = fmaf(v0.z, a.z, b.z); r0.w = fmaf(v0.w, a.w, b.w);
        r1.x = fmaf(v1.x, a.x, b.x); r1.y = fmaf(v1.y, a.y, b.y);
        r1.z = fmaf(v1.z, a.z, b.z); r1.w = fmaf(v1.w, a.w, b.w);
        r2.x = fmaf(v2.x, a.x, b.x); r2.y = fmaf(v2.y, a.y, b.y);
        r2.z = fmaf(v2.z, a.z, b.z); r2.w = fmaf(v2.w, a.w, b.w);
        r3.x = fmaf(v3.x, a.x, b.x); r3.y = fmaf(v3.y, a.y, b.y);
        r3.z = fmaf(v3.z, a.z, b.z); r3.w = fmaf(v3.w, a.w, b.w);
        yg[(size_t)(node     ) * F4 + grp] = r0;
        yg[(size_t)(node + 16) * F4 + grp] = r1;
        yg[(size_t)(node + 32) * F4 + grp] = r2;
        yg[(size_t)(node + 48) * F4 + grp] = r3;
    }
    for (; node < cnt; node += 16) {
        float4 v0 = xg[(size_t)node * F4 + grp];
        float4 r0;
        r0.x = fmaf(v0.x, a.x, b.x); r0.y = fmaf(v0.y, a.y, b.y);
        r0.z = fmaf(v0.z, a.z, b.z); r0.w = fmaf(v0.w, a.w, b.w);
        yg[(size_t)node * F4 + grp] = r0;
    }
}

extern "C" void kernel_launch(void* const* d_in, const int* in_sizes, int n_in,
                              void* d_out, int out_size, void* d_ws, size_t ws_size,
                              hipStream_t stream) {
    const float* x          = (const float*)d_in[0];
    const int*   n_node     = (const int*)d_in[1];
    const float* mean_scale = (const float*)d_in[2];
    const float* scale      = (const float*)d_in[3];
    const float* bias       = (const float*)d_in[4];
    float*       y          = (float*)d_out;

    const int n_graph = in_sizes[1];

    // coefficient buffer: A[G][128] + B[G][128] fp32 = n_graph*1KiB (1 MiB here)
    const size_t need = (size_t)n_graph * D_FEAT * 2 * sizeof(float);
    int     mode = 1;
    float4* coef = nullptr;
    if (d_ws != nullptr && ws_size >= need) { mode = 0; coef = (float4*)d_ws; }

    gn_stats<<<n_graph, BLOCK, 0, stream>>>(
        x, n_node, mean_scale, scale, bias, y, coef, n_graph, mode);
    gn_apply<<<n_graph, BLOCK, 0, stream>>>(
        x, n_node, y, coef, n_graph, mode);
}

// Round 2
// 475.030 us; speedup vs baseline: 1.1014x; 1.1014x over previous
//
#include <hip/hip_runtime.h>

#define D_FEAT 128
#define F4     (D_FEAT / 4)          // 32 float4 per node row
#define BLOCK  1024                  // 16 waves
#define GRID   256                   // persistent: 1 block per CU
#define FAST_NODES 512
#define PT     (FAST_NODES * F4 / BLOCK)   // 16 cached float4 per thread
#define EPS    1e-6f

// ---- block-cooperative sum of n_node[lo..hi) (uniform control flow) ----
__device__ __forceinline__ int coop_sum(const int* __restrict__ n_node,
                                        int lo, int hi, int t)
{
    __shared__ int s_red[16];
    __shared__ int s_tot;
    int my = 0;
    for (int i = lo + t; i < hi; i += BLOCK) my += n_node[i];
    #pragma unroll
    for (int o = 32; o; o >>= 1) my += __shfl_down(my, o);
    if ((t & 63) == 0) s_red[t >> 6] = my;
    __syncthreads();
    if (t == 0) {
        int tot = 0;
        #pragma unroll
        for (int w = 0; w < 16; w++) tot += s_red[w];
        s_tot = tot;
    }
    __syncthreads();
    return s_tot;
}

// ---- block reduce of (sum, sq) -> per-feature affine coefficients a,b ----
__device__ __forceinline__ void reduce_coef(
    float4 sum, float4 sq, float inv,
    const float4* __restrict__ ms4,
    const float4* __restrict__ sc4,
    const float4* __restrict__ bs4,
    int t, float4& a_out, float4& b_out)
{
    __shared__ float4 s_sum[16][32];
    __shared__ float4 s_sq [16][32];
    __shared__ float4 s_a[32];
    __shared__ float4 s_b[32];
    const int wave = t >> 6, lane = t & 63, grp = t & 31;

    sum.x += __shfl_down(sum.x, 32); sum.y += __shfl_down(sum.y, 32);
    sum.z += __shfl_down(sum.z, 32); sum.w += __shfl_down(sum.w, 32);
    sq.x  += __shfl_down(sq.x, 32);  sq.y  += __shfl_down(sq.y, 32);
    sq.z  += __shfl_down(sq.z, 32);  sq.w  += __shfl_down(sq.w, 32);
    if (lane < 32) { s_sum[wave][lane] = sum; s_sq[wave][lane] = sq; }
    __syncthreads();

    if (t < 32) {
        float4 S = make_float4(0.f, 0.f, 0.f, 0.f);
        float4 Q = make_float4(0.f, 0.f, 0.f, 0.f);
        #pragma unroll
        for (int w = 0; w < 16; w++) {
            float4 a4 = s_sum[w][t];
            float4 b4 = s_sq[w][t];
            S.x += a4.x; S.y += a4.y; S.z += a4.z; S.w += a4.w;
            Q.x += b4.x; Q.y += b4.y; Q.z += b4.z; Q.w += b4.w;
        }
        const float4 ms = ms4[t];
        const float4 sc = sc4[t];
        const float4 bs = bs4[t];
        float4 A, B;
        {
            float mean = S.x * inv, m = mean * ms.x;
            float var  = Q.x * inv - 2.f * m * mean + m * m;
            A.x = rsqrtf(var + EPS) * sc.x; B.x = bs.x - m * A.x;
        }
        {
            float mean = S.y * inv, m = mean * ms.y;
            float var  = Q.y * inv - 2.f * m * mean + m * m;
            A.y = rsqrtf(var + EPS) * sc.y; B.y = bs.y - m * A.y;
        }
        {
            float mean = S.z * inv, m = mean * ms.z;
            float var  = Q.z * inv - 2.f * m * mean + m * m;
            A.z = rsqrtf(var + EPS) * sc.z; B.z = bs.z - m * A.z;
        }
        {
            float mean = S.w * inv, m = mean * ms.w;
            float var  = Q.w * inv - 2.f * m * mean + m * m;
            A.w = rsqrtf(var + EPS) * sc.w; B.w = bs.w - m * A.w;
        }
        s_a[t] = A; s_b[t] = B;
    }
    __syncthreads();
    a_out = s_a[grp];
    b_out = s_b[grp];
}

__global__ __launch_bounds__(BLOCK, 4) void graphnorm_persist(
    const float* __restrict__ x,
    const int*   __restrict__ n_node,
    const float* __restrict__ mean_scale,
    const float* __restrict__ scale,
    const float* __restrict__ bias,
    float*       __restrict__ y,
    int n_graph)
{
    const int t    = threadIdx.x;
    const int grp  = t & 31;     // which float4 of the 128-feat row
    const int nsub = t >> 5;     // 0..31 : node sub-index (stride 32)
    const int nb   = gridDim.x;

    const float4* ms4 = (const float4*)mean_scale;
    const float4* sc4 = (const float4*)scale;
    const float4* bs4 = (const float4*)bias;

    int g = blockIdx.x;
    if (g >= n_graph) return;
    int node0 = coop_sum(n_node, 0, g, t);

    float4 v[PT];                   // register cache: one full graph
    float4 a_p, b_p;                // pending (previous graph) coefficients
    float4* yg_p = nullptr;         // pending store base
    int pend = 0;

    for (;;) {
        const int   cnt = n_node[g];
        const float inv = 1.0f / (float)cnt;
        const float4* __restrict__ xg = (const float4*)x + (size_t)node0 * F4;
        float4*       __restrict__ yg = (float4*)y       + (size_t)node0 * F4;

        if (cnt == FAST_NODES) {
            float4 sum = make_float4(0.f, 0.f, 0.f, 0.f);
            float4 sq  = make_float4(0.f, 0.f, 0.f, 0.f);
            if (pend) {
                // steady state: interleave store(prev, chunk i) / load(cur, chunk i)
                #pragma unroll
                for (int i = 0; i < PT; i++) {
                    const size_t idx = (size_t)(nsub + 32 * i) * F4 + grp;
                    float4 r;
                    r.x = fmaf(v[i].x, a_p.x, b_p.x);
                    r.y = fmaf(v[i].y, a_p.y, b_p.y);
                    r.z = fmaf(v[i].z, a_p.z, b_p.z);
                    r.w = fmaf(v[i].w, a_p.w, b_p.w);
                    yg_p[idx] = r;
                    float4 nv = xg[idx];
                    sum.x += nv.x; sum.y += nv.y; sum.z += nv.z; sum.w += nv.w;
                    sq.x  += nv.x * nv.x; sq.y += nv.y * nv.y;
                    sq.z  += nv.z * nv.z; sq.w += nv.w * nv.w;
                    v[i] = nv;
                }
            } else {
                #pragma unroll
                for (int i = 0; i < PT; i++) {
                    const size_t idx = (size_t)(nsub + 32 * i) * F4 + grp;
                    float4 nv = xg[idx];
                    sum.x += nv.x; sum.y += nv.y; sum.z += nv.z; sum.w += nv.w;
                    sq.x  += nv.x * nv.x; sq.y += nv.y * nv.y;
                    sq.z  += nv.z * nv.z; sq.w += nv.w * nv.w;
                    v[i] = nv;
                }
            }
            reduce_coef(sum, sq, inv, ms4, sc4, bs4, t, a_p, b_p);
            yg_p = yg;
            pend = 1;
        } else {
            // generic path: flush pending, then two-pass streaming
            if (pend) {
                #pragma unroll
                for (int i = 0; i < PT; i++) {
                    const size_t idx = (size_t)(nsub + 32 * i) * F4 + grp;
                    float4 r;
                    r.x = fmaf(v[i].x, a_p.x, b_p.x);
                    r.y = fmaf(v[i].y, a_p.y, b_p.y);
                    r.z = fmaf(v[i].z, a_p.z, b_p.z);
                    r.w = fmaf(v[i].w, a_p.w, b_p.w);
                    yg_p[idx] = r;
                }
                pend = 0;
            }
            float4 sum = make_float4(0.f, 0.f, 0.f, 0.f);
            float4 sq  = make_float4(0.f, 0.f, 0.f, 0.f);
            for (int node = nsub; node < cnt; node += 32) {
                float4 nv = xg[(size_t)node * F4 + grp];
                sum.x += nv.x; sum.y += nv.y; sum.z += nv.z; sum.w += nv.w;
                sq.x  += nv.x * nv.x; sq.y += nv.y * nv.y;
                sq.z  += nv.z * nv.z; sq.w += nv.w * nv.w;
            }
            float4 a, b;
            reduce_coef(sum, sq, inv, ms4, sc4, bs4, t, a, b);
            for (int node = nsub; node < cnt; node += 32) {
                const size_t idx = (size_t)node * F4 + grp;
                float4 nv = xg[idx];
                float4 r;
                r.x = fmaf(nv.x, a.x, b.x);
                r.y = fmaf(nv.y, a.y, b.y);
                r.z = fmaf(nv.z, a.z, b.z);
                r.w = fmaf(nv.w, a.w, b.w);
                yg[idx] = r;
            }
        }

        const int next = g + nb;
        if (next >= n_graph) break;
        node0 += coop_sum(n_node, g, next, t);   // offset of graph `next`
        g = next;
    }

    // drain the last pending store
    if (pend) {
        #pragma unroll
        for (int i = 0; i < PT; i++) {
            const size_t idx = (size_t)(nsub + 32 * i) * F4 + grp;
            float4 r;
            r.x = fmaf(v[i].x, a_p.x, b_p.x);
            r.y = fmaf(v[i].y, a_p.y, b_p.y);
            r.z = fmaf(v[i].z, a_p.z, b_p.z);
            r.w = fmaf(v[i].w, a_p.w, b_p.w);
            yg_p[idx] = r;
        }
    }
}

extern "C" void kernel_launch(void* const* d_in, const int* in_sizes, int n_in,
                              void* d_out, int out_size, void* d_ws, size_t ws_size,
                              hipStream_t stream) {
    const float* x          = (const float*)d_in[0];
    const int*   n_node     = (const int*)d_in[1];
    const float* mean_scale = (const float*)d_in[2];
    const float* scale      = (const float*)d_in[3];
    const float* bias       = (const float*)d_in[4];
    float*       y          = (float*)d_out;

    const int n_graph = in_sizes[1];
    const int grid    = (n_graph < GRID) ? n_graph : GRID;

    graphnorm_persist<<<grid, BLOCK, 0, stream>>>(
        x, n_node, mean_scale, scale, bias, y, n_graph);
}

// Round 4
// 443.541 us; speedup vs baseline: 1.1796x; 1.0710x over previous
//
#include <hip/hip_runtime.h>

#define D_FEAT 128
#define F4ALL  (D_FEAT / 4)      // 32 float4 per full node row
#define F4H    (F4ALL / 2)       // 16 float4 per half row (64 features)
#define BLOCK  512               // 8 waves
#define FAST_NODES 512
#define PT     16                // 512 nodes * 16 f4 / 512 thr
#define EPS    1e-6f

// ---- block-cooperative sum of n_node[0..g) (uniform control flow) ----
__device__ __forceinline__ int graph_offset(const int* __restrict__ n_node,
                                            int g, int t)
{
    __shared__ int s_red[8];
    __shared__ int s_off;
    int my = 0;
    for (int i = t; i < g; i += BLOCK) my += n_node[i];
    #pragma unroll
    for (int o = 32; o; o >>= 1) my += __shfl_down(my, o);
    if ((t & 63) == 0) s_red[t >> 6] = my;
    __syncthreads();
    if (t == 0) {
        int tot = 0;
        #pragma unroll
        for (int w = 0; w < 8; w++) tot += s_red[w];
        s_off = tot;
    }
    __syncthreads();
    return s_off;
}

// ---- block reduce of (sum, sq) over 32 node-lanes -> per-feature a,b ----
// grp = t & 15 selects one of 16 float4 (= 64 features of this half).
__device__ __forceinline__ void reduce_coef(
    float4 sum, float4 sq, float inv,
    const float4* __restrict__ ms4,   // pre-offset by half
    const float4* __restrict__ sc4,
    const float4* __restrict__ bs4,
    int t, float4& a_out, float4& b_out)
{
    __shared__ float4 s_sum[8][16];
    __shared__ float4 s_sq [8][16];
    __shared__ float4 s_a[16];
    __shared__ float4 s_b[16];
    const int wave = t >> 6, lane = t & 63, grp = t & 15;

    // within wave: 4 node-lanes per grp -> fold by 32 then 16
    sum.x += __shfl_down(sum.x, 32); sum.y += __shfl_down(sum.y, 32);
    sum.z += __shfl_down(sum.z, 32); sum.w += __shfl_down(sum.w, 32);
    sq.x  += __shfl_down(sq.x, 32);  sq.y  += __shfl_down(sq.y, 32);
    sq.z  += __shfl_down(sq.z, 32);  sq.w  += __shfl_down(sq.w, 32);
    sum.x += __shfl_down(sum.x, 16); sum.y += __shfl_down(sum.y, 16);
    sum.z += __shfl_down(sum.z, 16); sum.w += __shfl_down(sum.w, 16);
    sq.x  += __shfl_down(sq.x, 16);  sq.y  += __shfl_down(sq.y, 16);
    sq.z  += __shfl_down(sq.z, 16);  sq.w  += __shfl_down(sq.w, 16);
    if (lane < 16) { s_sum[wave][lane] = sum; s_sq[wave][lane] = sq; }
    __syncthreads();

    if (t < 16) {
        float4 S = make_float4(0.f, 0.f, 0.f, 0.f);
        float4 Q = make_float4(0.f, 0.f, 0.f, 0.f);
        #pragma unroll
        for (int w = 0; w < 8; w++) {
            float4 a4 = s_sum[w][t];
            float4 b4 = s_sq[w][t];
            S.x += a4.x; S.y += a4.y; S.z += a4.z; S.w += a4.w;
            Q.x += b4.x; Q.y += b4.y; Q.z += b4.z; Q.w += b4.w;
        }
        const float4 ms = ms4[t];
        const float4 sc = sc4[t];
        const float4 bs = bs4[t];
        float4 A, B;
        {
            float mean = S.x * inv, m = mean * ms.x;
            float var  = Q.x * inv - 2.f * m * mean + m * m;
            A.x = rsqrtf(var + EPS) * sc.x; B.x = bs.x - m * A.x;
        }
        {
            float mean = S.y * inv, m = mean * ms.y;
            float var  = Q.y * inv - 2.f * m * mean + m * m;
            A.y = rsqrtf(var + EPS) * sc.y; B.y = bs.y - m * A.y;
        }
        {
            float mean = S.z * inv, m = mean * ms.z;
            float var  = Q.z * inv - 2.f * m * mean + m * m;
            A.z = rsqrtf(var + EPS) * sc.z; B.z = bs.z - m * A.z;
        }
        {
            float mean = S.w * inv, m = mean * ms.w;
            float var  = Q.w * inv - 2.f * m * mean + m * m;
            A.w = rsqrtf(var + EPS) * sc.w; B.w = bs.w - m * A.w;
        }
        s_a[t] = A; s_b[t] = B;
    }
    __syncthreads();
    a_out = s_a[grp];
    b_out = s_b[grp];
}

// One block = one (graph, feature-half). Fully independent: the block sees
// all nodes of its graph for its 64 features, so mean/var need no
// cross-block exchange. 2 blocks/CU co-resident cover each other's
// reduce bubbles and retire gaps.
__global__ __launch_bounds__(BLOCK, 4) void gn_half(
    const float* __restrict__ x,
    const int*   __restrict__ n_node,
    const float* __restrict__ mean_scale,
    const float* __restrict__ scale,
    const float* __restrict__ bias,
    float*       __restrict__ y,
    int n_graph)
{
    const int b    = blockIdx.x;
    const int g    = b >> 1;         // graph
    const int h    = b & 1;          // feature half: 0 -> feats 0..63, 1 -> 64..127
    const int t    = threadIdx.x;
    const int grp  = t & 15;         // which float4 within the half row
    const int nsub = t >> 4;         // 0..31 : node sub-index (stride 32)

    if (g >= n_graph) return;

    const int node0 = graph_offset(n_node, g, t);
    const int cnt   = n_node[g];
    const float inv = 1.0f / (float)cnt;

    const float4* __restrict__ xg = (const float4*)x + (size_t)node0 * F4ALL + h * F4H;
    float4*       __restrict__ yg = (float4*)y       + (size_t)node0 * F4ALL + h * F4H;
    const float4* ms4 = (const float4*)mean_scale + h * F4H;
    const float4* sc4 = (const float4*)scale      + h * F4H;
    const float4* bs4 = (const float4*)bias       + h * F4H;

    float4 sum = make_float4(0.f, 0.f, 0.f, 0.f);
    float4 sq  = make_float4(0.f, 0.f, 0.f, 0.f);

    if (cnt == FAST_NODES) {
        // ---- pass 1: register-cached coalesced loads ----
        float4 v[PT];
        #pragma unroll
        for (int i = 0; i < PT; i++) {
            const size_t idx = (size_t)(nsub + 32 * i) * F4ALL + grp;
            v[i] = xg[idx];
            sum.x += v[i].x; sum.y += v[i].y; sum.z += v[i].z; sum.w += v[i].w;
            sq.x  += v[i].x * v[i].x; sq.y += v[i].y * v[i].y;
            sq.z  += v[i].z * v[i].z; sq.w += v[i].w * v[i].w;
        }

        float4 a, b;
        reduce_coef(sum, sq, inv, ms4, sc4, bs4, t, a, b);

        // ---- pass 2: pure-register affine + coalesced stores ----
        #pragma unroll
        for (int i = 0; i < PT; i++) {
            const size_t idx = (size_t)(nsub + 32 * i) * F4ALL + grp;
            float4 r;
            r.x = fmaf(v[i].x, a.x, b.x);
            r.y = fmaf(v[i].y, a.y, b.y);
            r.z = fmaf(v[i].z, a.z, b.z);
            r.w = fmaf(v[i].w, a.w, b.w);
            yg[idx] = r;
        }
    } else {
        // ---- generic path: two-pass streaming (L2/L3-assisted re-read) ----
        for (int node = nsub; node < cnt; node += 32) {
            float4 nv = xg[(size_t)node * F4ALL + grp];
            sum.x += nv.x; sum.y += nv.y; sum.z += nv.z; sum.w += nv.w;
            sq.x  += nv.x * nv.x; sq.y += nv.y * nv.y;
            sq.z  += nv.z * nv.z; sq.w += nv.w * nv.w;
        }
        float4 a, b;
        reduce_coef(sum, sq, inv, ms4, sc4, bs4, t, a, b);
        for (int node = nsub; node < cnt; node += 32) {
            const size_t idx = (size_t)node * F4ALL + grp;
            float4 nv = xg[idx];
            float4 r;
            r.x = fmaf(nv.x, a.x, b.x);
            r.y = fmaf(nv.y, a.y, b.y);
            r.z = fmaf(nv.z, a.z, b.z);
            r.w = fmaf(nv.w, a.w, b.w);
            yg[idx] = r;
        }
    }
}

extern "C" void kernel_launch(void* const* d_in, const int* in_sizes, int n_in,
                              void* d_out, int out_size, void* d_ws, size_t ws_size,
                              hipStream_t stream) {
    const float* x          = (const float*)d_in[0];
    const int*   n_node     = (const int*)d_in[1];
    const float* mean_scale = (const float*)d_in[2];
    const float* scale      = (const float*)d_in[3];
    const float* bias       = (const float*)d_in[4];
    float*       y          = (float*)d_out;

    const int n_graph = in_sizes[1];

    gn_half<<<2 * n_graph, BLOCK, 0, stream>>>(
        x, n_node, mean_scale, scale, bias, y, n_graph);
}